// Round 6
// baseline (1172.636 us; speedup 1.0000x reference)
//
#include <hip/hip_runtime.h>
#include <hip/hip_bf16.h>
#include <math.h>

typedef __bf16 bf16_t;
typedef __bf16 bf16x8 __attribute__((ext_vector_type(8)));
typedef float f32x4 __attribute__((ext_vector_type(4)));
typedef unsigned short u16;
typedef unsigned int u32;

#define NB   40
#define NT   20
#define FEA  200
#define HD   1024
#define NOUT 1095
#define NL   12
#define M_ROWS 800      // NB*NT
#define UPITCH 196      // fp32 pitch for U in LDS (192 + 4 pad)
#define NBLK 160        // fused grid: 16 col-blocks x 10 batch-groups

// ---------------------------------------------------------------------------
// Transpose+convert, no-LDS: thread owns dst row c (= src col c); reads 64
// consecutive src rows (coalesced across threads), packs bf16 in regs, writes
// 8x uint4. dst[c][k] zero-padded to [Np][Kp]. blockIdx.z = layer.
// ---------------------------------------------------------------------------
__global__ __launch_bounds__(256)
void transpose_convert(const float* __restrict__ src, bf16_t* __restrict__ dst,
                       int srcK, int srcN, int Kp, int Np)
{
    src += (size_t)blockIdx.z * srcK * srcN;
    dst += (size_t)blockIdx.z * Np * Kp;
    const int c = blockIdx.x * 256 + threadIdx.x;
    if (c >= Np) return;
    const int k0 = blockIdx.y << 6;
    const bool live = (c < srcN);

    u32 pk[32];
    #pragma unroll
    for (int j = 0; j < 64; j += 2) {
        const int g0 = k0 + j, g1 = k0 + j + 1;
        float v0 = (live && g0 < srcK) ? src[(size_t)g0 * srcN + c] : 0.f;
        float v1 = (live && g1 < srcK) ? src[(size_t)g1 * srcN + c] : 0.f;
        bf16_t b0 = (bf16_t)v0, b1 = (bf16_t)v1;
        pk[j >> 1] = (u32)*(const u16*)&b0 | ((u32)*(const u16*)&b1 << 16);
    }
    uint4* dp = (uint4*)(dst + (size_t)c * Kp + k0);
    #pragma unroll
    for (int q = 0; q < 8; q++) dp[q] = ((const uint4*)pk)[q];
}

// x [800][200] fp32 -> xb [800][256] bf16 zero-padded.
__global__ __launch_bounds__(256)
void convert_pad_x(const float* __restrict__ src, bf16_t* __restrict__ dst)
{
    const int m = blockIdx.x, k = threadIdx.x;
    dst[m * 256 + k] = (bf16_t)((k < FEA) ? src[(size_t)m * FEA + k] : 0.f);
}

// ---------------------------------------------------------------------------
// Grid barrier: single-use counter, device-scope release/acquire.
// NBLK=160 blocks, 1 per CU -> co-resident.
// ---------------------------------------------------------------------------
__device__ __forceinline__ void grid_barrier(unsigned* cnt, unsigned target)
{
    __syncthreads();
    if (threadIdx.x == 0) {
        __threadfence();
        __hip_atomic_fetch_add(cnt, 1u, __ATOMIC_RELEASE, __HIP_MEMORY_SCOPE_AGENT);
        while (__hip_atomic_load(cnt, __ATOMIC_ACQUIRE, __HIP_MEMORY_SCOPE_AGENT) < target)
            __builtin_amdgcn_s_sleep(1);
    }
    __syncthreads();
}

__device__ __forceinline__ float fast_sigmoid(float v) {
    return 1.f / (1.f + __expf(-v));
}
__device__ __forceinline__ float fast_tanh(float v) {
    return 1.f - 2.f / (__expf(2.f * v) + 1.f);
}

// ---------------------------------------------------------------------------
// Dense GEMM tile, 128 rows x 64 cols per block (8 waves, wave = row-subtile).
// Batched unroll-4 K loads (128 k per superiter) for MLP. Direct-fragment.
// Layouts (verified): A[m=l16][k=quad*8+j], B[n=l16][k=quad*8+j],
// D col=l16, row=quad*4+reg.
// ---------------------------------------------------------------------------
template<bool OUT_F32, bool RELU>
__device__ __forceinline__
void gemm_tile(const bf16_t* __restrict__ A, const bf16_t* __restrict__ Bt,
               const float* __restrict__ bias, void* __restrict__ C,
               int M, int Nstore, int Ks, int n0, int mb)
{
    const int tid = threadIdx.x;
    const int w = tid >> 6, lane = tid & 63, quad = lane >> 4, l16 = lane & 15;
    const int r0 = (mb * 8 + w) << 4;

    int arow = r0 + l16; if (arow > M - 1) arow = M - 1;
    const bf16_t* ap = A + (size_t)arow * Ks + quad * 8;
    const bf16_t* bp[4];
    #pragma unroll
    for (int ct = 0; ct < 4; ct++)
        bp[ct] = Bt + (size_t)(n0 + ct * 16 + l16) * Ks + quad * 8;

    f32x4 acc[4];
    #pragma unroll
    for (int i = 0; i < 4; i++) acc[i] = (f32x4){0.f, 0.f, 0.f, 0.f};

    for (int k0 = 0; k0 < Ks; k0 += 128) {
        bf16x8 a[4], b[4][4];
        #pragma unroll
        for (int u = 0; u < 4; u++) {
            a[u] = *(const bf16x8*)(ap + k0 + u * 32);
            #pragma unroll
            for (int ct = 0; ct < 4; ct++)
                b[u][ct] = *(const bf16x8*)(bp[ct] + k0 + u * 32);
        }
        #pragma unroll
        for (int u = 0; u < 4; u++)
            #pragma unroll
            for (int ct = 0; ct < 4; ct++)
                acc[ct] = __builtin_amdgcn_mfma_f32_16x16x32_bf16(a[u], b[u][ct], acc[ct], 0, 0, 0);
    }

    #pragma unroll
    for (int ct = 0; ct < 4; ct++) {
        const int col = n0 + ct * 16 + l16;
        if (col >= Nstore) continue;
        const float bv = bias ? bias[col] : 0.f;
        #pragma unroll
        for (int i = 0; i < 4; i++) {
            const int m = r0 + quad * 4 + i;
            if (m < M) {
                float v = acc[ct][i] + bv;
                if (RELU) v = v > 0.f ? v : 0.f;
                if (OUT_F32) ((float*)C)[(size_t)m * Nstore + col] = v;
                else         ((bf16_t*)C)[(size_t)m * Nstore + col] = (bf16_t)v;
            }
        }
    }
}

// ---------------------------------------------------------------------------
// One SRU layer for this block (n0 = 64 h-cols, bi = 4 batches = 80 rows).
// 8 waves: cg = w&3 -> col-tiles 3cg..3cg+2 (12 total = 192 U cols);
// rg = w>>2 -> row-tiles 3rg..3rg+2 (rows padded 80->96, junk rows dropped).
// Batched unroll-4 K loads. U -> LDS fp32; 20-step scan on threads 0..255.
// ---------------------------------------------------------------------------
__device__ __forceinline__
void sru_tile(const bf16_t* __restrict__ hin, bf16_t* __restrict__ hout,
              const bf16_t* __restrict__ Wt, const float* __restrict__ c0,
              const float* __restrict__ bvec, float* __restrict__ cout,
              int n0, int bi, float* __restrict__ Ul)
{
    const int tid = threadIdx.x;
    const int w = tid >> 6, lane = tid & 63, quad = lane >> 4, l16 = lane & 15;
    const int cg = w & 3, rg = w >> 2;

    f32x4 acc[3][3];
    #pragma unroll
    for (int rt = 0; rt < 3; rt++)
        #pragma unroll
        for (int ct = 0; ct < 3; ct++) acc[rt][ct] = (f32x4){0.f, 0.f, 0.f, 0.f};

    const bf16_t* bp[3];
    #pragma unroll
    for (int ct = 0; ct < 3; ct++) {
        const int ctt = cg * 3 + ct;   // 0..11; gate=ctt>>2, 16-col chunk=ctt&3
        bp[ct] = Wt + (size_t)((ctt >> 2) * HD + n0 + ((ctt & 3) << 4) + l16) * HD + quad * 8;
    }
    const bf16_t* ap[3];
    #pragma unroll
    for (int rt = 0; rt < 3; rt++) {
        int lr = (rg * 3 + rt) * 16 + l16;          // 0..95
        if (lr > 79) lr = 79;                       // clamp (junk rows dropped)
        ap[rt] = hin + (size_t)(bi * 80 + lr) * HD + quad * 8;
    }

    for (int k0 = 0; k0 < HD; k0 += 128) {
        bf16x8 a[4][3], b[4][3];
        #pragma unroll
        for (int u = 0; u < 4; u++) {
            #pragma unroll
            for (int rt = 0; rt < 3; rt++) a[u][rt] = *(const bf16x8*)(ap[rt] + k0 + u * 32);
            #pragma unroll
            for (int ct = 0; ct < 3; ct++) b[u][ct] = *(const bf16x8*)(bp[ct] + k0 + u * 32);
        }
        #pragma unroll
        for (int u = 0; u < 4; u++)
            #pragma unroll
            for (int rt = 0; rt < 3; rt++)
                #pragma unroll
                for (int ct = 0; ct < 3; ct++)
                    acc[rt][ct] = __builtin_amdgcn_mfma_f32_16x16x32_bf16(a[u][rt], b[u][ct], acc[rt][ct], 0, 0, 0);
    }

    #pragma unroll
    for (int rt = 0; rt < 3; rt++)
        #pragma unroll
        for (int ct = 0; ct < 3; ct++) {
            const int col = (cg * 3 + ct) * 16 + l16;
            #pragma unroll
            for (int i = 0; i < 4; i++) {
                const int row = (rg * 3 + rt) * 16 + quad * 4 + i;
                if (row < 80) Ul[row * UPITCH + col] = acc[rt][ct][i];
            }
        }
    __syncthreads();

    if (tid < 256) {
        const int bl = tid >> 6, nn = tid & 63, bg = bi * 4 + bl;
        float c = c0[(size_t)bg * HD + n0 + nn];
        const float bfb = bvec[n0 + nn], brb = bvec[HD + n0 + nn];

        #pragma unroll 4
        for (int t = 0; t < NT; t++) {
            const float* u = &Ul[(bl * NT + t) * UPITCH];
            const float xt = u[nn];
            const float f = fast_sigmoid(u[64 + nn] + bfb);
            const float r = fast_sigmoid(u[128 + nn] + brb);
            c = f * c + (1.f - f) * xt;
            const size_t gi = (size_t)(bg * NT + t) * HD + n0 + nn;
            const float hp = (float)hin[gi];
            hout[gi] = (bf16_t)(r * fast_tanh(c) + (1.f - r) * hp);
        }
        cout[(size_t)bg * HD + n0 + nn] = c;
    }
}

// ---------------------------------------------------------------------------
// Fused network: dense1 + 12 SRU layers + dense3(relu) + dense4.
// Grid = 160 blocks x 512 threads (8 waves -> 2 waves/SIMD for MLP).
// ---------------------------------------------------------------------------
__global__ __launch_bounds__(512)
void fused_net(const bf16_t* __restrict__ xb, const bf16_t* __restrict__ w1t,
               const float* __restrict__ b1,  const bf16_t* __restrict__ wt,
               const float* __restrict__ c0all, const float* __restrict__ ball,
               const bf16_t* __restrict__ w3t, const float* __restrict__ b3,
               const bf16_t* __restrict__ w4t, const float* __restrict__ b4,
               bf16_t* h0, bf16_t* h1, bf16_t* g,
               float* __restrict__ out, float* __restrict__ hid_out,
               unsigned* __restrict__ bar)
{
    __shared__ float Ul[80 * UPITCH];   // 62720 B
    const int bx = blockIdx.x;

    // phase 0: h0 = xb @ w1t + b1   (16 col x 7 row tiles = 112 <= 160)
    if (bx < 16 * 7)
        gemm_tile<false, false>(xb, w1t, b1, h0, M_ROWS, HD, 256, (bx & 15) << 6, bx >> 4);
    grid_barrier(bar + 0, NBLK);

    // phases 1..12: SRU layers, ping-pong h0 <-> h1
    const int n0 = (bx & 15) << 6, bi = bx >> 4;
    bf16_t* hi = h0; bf16_t* ho = h1;
    for (int l = 0; l < NL; l++) {
        sru_tile(hi, ho, wt + (size_t)l * 3 * HD * HD,
                 c0all + (size_t)l * NB * HD, ball + (size_t)l * 2 * HD,
                 hid_out + (size_t)l * NB * HD, n0, bi, Ul);
        grid_barrier(bar + 1 + l, NBLK);
        bf16_t* tmp = hi; hi = ho; ho = tmp;
    }
    // final h in h0

    // phase 13: g = relu(h0 @ w3t + b3)
    if (bx < 16 * 7)
        gemm_tile<false, true>(h0, w3t, b3, g, M_ROWS, HD, HD, (bx & 15) << 6, bx >> 4);
    grid_barrier(bar + 13, NBLK);

    // phase 14: out = g @ w4t + b4   (18 col x 7 row tiles = 126 <= 160)
    if (bx < 18 * 7)
        gemm_tile<true, false>(g, w4t, b4, out, M_ROWS, NOUT, HD, (bx % 18) << 6, bx / 18);
}

// ---------------------------------------------------------------------------
extern "C" void kernel_launch(void* const* d_in, const int* in_sizes, int n_in,
                              void* d_out, int out_size, void* d_ws, size_t ws_size,
                              hipStream_t stream)
{
    const float* x      = (const float*)d_in[0];
    const float* hidden = (const float*)d_in[1];
    const float* W1     = (const float*)d_in[2];
    const float* b1     = (const float*)d_in[3];
    const float* sruW   = (const float*)d_in[4];
    const float* srub   = (const float*)d_in[5];
    const float* W3     = (const float*)d_in[6];
    const float* b3     = (const float*)d_in[7];
    const float* W4     = (const float*)d_in[8];
    const float* b4     = (const float*)d_in[9];

    float* out     = (float*)d_out;
    float* hid_out = out + (size_t)M_ROWS * NOUT;   // [12,40,1024] fp32

    // h0 (bf16, 1.64 MB) aliases d_out's out0 region (3.50 MB fp32): dead by
    // phase 14, which reads only g and fully overwrites it.
    bf16_t* h0 = (bf16_t*)d_out;

    char* ws = (char*)d_ws;
    const size_t SZ_WT  = (size_t)NL * 3 * HD * HD * 2;    // 75,497,472
    const size_t SZ_W1  = (size_t)HD * 256 * 2;
    const size_t SZ_W3  = (size_t)HD * HD * 2;
    const size_t SZ_W4  = (size_t)1152 * HD * 2;
    const size_t SZ_XB  = (size_t)M_ROWS * 256 * 2;
    const size_t SZ_H   = (size_t)M_ROWS * HD * 2;

    bf16_t* wt  = (bf16_t*)ws;
    bf16_t* w1t = (bf16_t*)(ws + SZ_WT);
    bf16_t* w3t = (bf16_t*)(ws + SZ_WT + SZ_W1);
    bf16_t* w4t = (bf16_t*)(ws + SZ_WT + SZ_W1 + SZ_W3);
    bf16_t* xb  = (bf16_t*)(ws + SZ_WT + SZ_W1 + SZ_W3 + SZ_W4);
    bf16_t* h1  = (bf16_t*)(ws + SZ_WT + SZ_W1 + SZ_W3 + SZ_W4 + SZ_XB);
    bf16_t* g   = (bf16_t*)(ws + SZ_WT + SZ_W1 + SZ_W3 + SZ_W4 + SZ_XB + SZ_H);
    unsigned* bar = (unsigned*)(ws + SZ_WT + SZ_W1 + SZ_W3 + SZ_W4 + SZ_XB + 2 * SZ_H);

    hipMemsetAsync(bar, 0, 16 * sizeof(unsigned), stream);

    // prep: convert + transpose all weights to bf16 [n][k]
    convert_pad_x<<<M_ROWS, 256, 0, stream>>>(x, xb);
    transpose_convert<<<dim3(4, 4, 1),    256, 0, stream>>>(W1,   w1t, FEA, HD,    256, HD);
    transpose_convert<<<dim3(12, 16, NL), 256, 0, stream>>>(sruW, wt,  HD,  3*HD, HD,  3*HD);
    transpose_convert<<<dim3(4, 16, 1),   256, 0, stream>>>(W3,   w3t, HD,  HD,   HD,  HD);
    transpose_convert<<<dim3(5, 16, 1),   256, 0, stream>>>(W4,   w4t, HD,  NOUT, HD,  1152);

    fused_net<<<dim3(NBLK), 512, 0, stream>>>(
        xb, w1t, b1, wt, hidden, srub, w3t, b3, w4t, b4,
        h0, h1, g, out, hid_out, bar);
}